// Round 9
// baseline (6265.808 us; speedup 1.0000x reference)
//
#include <hip/hip_runtime.h>
#include <math.h>

// AnyNet stereo forward, fp32. Round 9: unpadded conv with 32-bit-offset
// addressing (SGPR base + int offsets; no 64-bit row pointers to hoist),
// branch-free masked loads (clamped offset + 0/1 multiply), 2-deep ci
// pipeline, __launch_bounds__(256,3) VGPR cap. No padding -> no memsets.

#define FULL_H 512
#define FULL_W 1280
#define NB 8
#define NPIX (NB * FULL_H * FULL_W)   // 5,242,880

// ---------------- stage-0 L1 cost volume ----------------
__global__ __launch_bounds__(256) void cost0_k(const float* __restrict__ fl,
                                               const float* __restrict__ fr,
                                               float* __restrict__ cost) {
    const int H = 32, W = 80, D = 12, C = 8;
    int idx = blockIdx.x * 256 + threadIdx.x;
    int total = NB * D * H * W;
    if (idx >= total) return;
    int w = idx % W; int t = idx / W;
    int h = t % H; t /= H;
    int d = t % D; int b = t / D;
    int src = w - d;
    float acc = 0.f;
    for (int c = 0; c < C; ++c) {
        int base = ((b * C + c) * H + h) * W;
        float flv = fl[base + w];
        float frv = (src >= 0) ? fr[base + src] : 0.f;
        acc += fabsf(flv - frv);
    }
    cost[((b * D + d) * H + h) * W + w] = acc;
}

// ---------------- residual (warped) cost volume ----------------
__global__ __launch_bounds__(256) void costres_k(const float* __restrict__ fl,
                                                 const float* __restrict__ fr,
                                                 const float* __restrict__ wf,
                                                 float* __restrict__ cost,
                                                 int H, int W) {
    const int C = 8, S = 5;
    int idx = blockIdx.x * 256 + threadIdx.x;
    int total = NB * S * H * W;
    if (idx >= total) return;
    int w = idx % W; int t = idx / W;
    int h = t % H; t /= H;
    int s = t % S; int b = t / S;
    float disp  = wf[(b * H + h) * W + w];
    float shift = (float)(s - 2);
    float xs  = (float)w - (disp - shift);
    float x0f = floorf(xs);
    float w1  = xs - x0f;
    float x0fc = fminf(fmaxf(x0f, -2.f), (float)W);
    int x0 = (int)x0fc;
    int x1 = x0 + 1;
    float m0 = (x0 >= 0 && x0 <= W - 1) ? (1.f - w1) : 0.f;
    float m1 = (x1 >= 0 && x1 <= W - 1) ? w1 : 0.f;
    int x0c = min(max(x0, 0), W - 1);
    int x1c = min(max(x1, 0), W - 1);
    float acc = 0.f;
    const float* flb = fl + ((b * C) * H + h) * W;
    const float* frb = fr + ((b * C) * H + h) * W;
    for (int c = 0; c < C; ++c) {
        float v = frb[x0c] * m0 + frb[x1c] * m1;
        acc += fabsf(flb[w] - v);
        flb += H * W;
        frb += H * W;
    }
    cost[idx] = acc;
}

// ---------------- unpadded, 32-bit-offset, ci-pipelined 3x3x3 conv3d ----------------
// x: [B,CIN,D,H,W]  wg: [COUT,CIN,27]  y: [B,COUT,D,H,W]
// Each thread: WT consecutive w outputs x all COUT. W % WT == 0, WT in {2,4}.
template <int CIN, int COUT, int WT, bool RELU>
__global__ __launch_bounds__(256, 3) void convf_k(const float* __restrict__ x,
                                                  const float* __restrict__ wg,
                                                  float* __restrict__ y,
                                                  int D, int H, int W,
                                                  int nstrips) {
    __shared__ __align__(16) float wl[CIN * 27 * COUT];
    for (int i = threadIdx.x; i < CIN * 27 * COUT; i += 256) {
        int co = i % COUT; int rest = i / COUT;
        int tap = rest % 27; int ci = rest / 27;
        wl[i] = wg[(co * CIN + ci) * 27 + tap];
    }
    __syncthreads();

    int idx = blockIdx.x * 256 + threadIdx.x;
    if (idx >= nstrips) return;
    const int SW = W / WT;
    int sw = idx % SW; int t = idx / SW;
    int h = t % H; t /= H;
    int d = t % D; int b = t / D;
    const int wbase = sw * WT;
    const int HW = H * W;
    const int chs = D * HW;

    // 32-bit addressing: one thread offset + 9 row-relative offsets (masked).
    const int off0 = b * CIN * chs + d * HW + h * W + wbase;
    int rowrel[9];
    float rowm[9];
#pragma unroll
    for (int r = 0; r < 9; ++r) {
        int kd = r / 3, kh = r % 3;
        int dd = d + kd - 1, hh = h + kh - 1;
        bool ok = ((unsigned)dd < (unsigned)D) && ((unsigned)hh < (unsigned)H);
        rowrel[r] = ok ? ((kd - 1) * HW + (kh - 1) * W) : 0;  // 0 = safe center row
        rowm[r] = ok ? 1.f : 0.f;
    }
    const bool haslo = (wbase > 0);
    const bool hashi = (wbase + WT < W);
    const int lo_off = haslo ? -1 : 0;
    const int hi_off = hashi ? WT : (WT - 1);
    const float mlo = haslo ? 1.f : 0.f;
    const float mhi = hashi ? 1.f : 0.f;

    float acc[COUT][WT];
#pragma unroll
    for (int co = 0; co < COUT; ++co)
#pragma unroll
        for (int wt = 0; wt < WT; ++wt) acc[co][wt] = 0.f;

    float A[9][WT + 2];

#define LOADCI(BUF, CIDX) do {                                                \
    const int o_ = off0 + (CIDX) * chs;                                       \
    _Pragma("unroll")                                                         \
    for (int r_ = 0; r_ < 9; ++r_) {                                          \
        const float* row_ = x + (o_ + rowrel[r_]);                            \
        const float m_ = rowm[r_];                                            \
        BUF[r_][0] = row_[lo_off] * (m_ * mlo);                               \
        if constexpr (WT == 2) {                                              \
            float2 v_ = *reinterpret_cast<const float2*>(row_);               \
            BUF[r_][1] = v_.x * m_; BUF[r_][2] = v_.y * m_;                   \
        } else {                                                              \
            float4 v_ = *reinterpret_cast<const float4*>(row_);               \
            BUF[r_][1] = v_.x * m_; BUF[r_][2] = v_.y * m_;                   \
            BUF[r_][3] = v_.z * m_; BUF[r_][4] = v_.w * m_;                   \
        }                                                                     \
        BUF[r_][WT + 1] = row_[hi_off] * (m_ * mhi);                          \
    } } while (0)

#define FMACI(BUF, CIDX) do {                                                 \
    const float* wc_ = wl + (CIDX) * 27 * COUT;                               \
    _Pragma("unroll")                                                         \
    for (int r_ = 0; r_ < 9; ++r_) {                                          \
        _Pragma("unroll")                                                     \
        for (int kw_ = 0; kw_ < 3; ++kw_) {                                   \
            const float* wp_ = wc_ + (r_ * 3 + kw_) * COUT;                   \
            if constexpr (COUT == 1) {                                        \
                float wv_ = wp_[0];                                           \
                _Pragma("unroll")                                             \
                for (int wt_ = 0; wt_ < WT; ++wt_)                            \
                    acc[0][wt_] = fmaf(BUF[r_][wt_ + kw_], wv_, acc[0][wt_]); \
            } else {                                                          \
                _Pragma("unroll")                                             \
                for (int q_ = 0; q_ < COUT / 4; ++q_) {                       \
                    float4 w4_ = reinterpret_cast<const float4*>(wp_)[q_];    \
                    _Pragma("unroll")                                         \
                    for (int wt_ = 0; wt_ < WT; ++wt_) {                      \
                        float xv_ = BUF[r_][wt_ + kw_];                       \
                        acc[q_ * 4 + 0][wt_] = fmaf(xv_, w4_.x, acc[q_ * 4 + 0][wt_]); \
                        acc[q_ * 4 + 1][wt_] = fmaf(xv_, w4_.y, acc[q_ * 4 + 1][wt_]); \
                        acc[q_ * 4 + 2][wt_] = fmaf(xv_, w4_.z, acc[q_ * 4 + 2][wt_]); \
                        acc[q_ * 4 + 3][wt_] = fmaf(xv_, w4_.w, acc[q_ * 4 + 3][wt_]); \
                    }                                                         \
                }                                                             \
            }                                                                 \
        }                                                                     \
    } } while (0)

    if constexpr (CIN == 1) {
        LOADCI(A, 0);
        FMACI(A, 0);
    } else {
        float Bf[9][WT + 2];
        LOADCI(A, 0);
        for (int ci = 0; ci < CIN; ci += 2) {   // CIN even (4 or 16)
            LOADCI(Bf, ci + 1);
            FMACI(A, ci);
            if (ci + 2 < CIN) LOADCI(A, ci + 2);
            FMACI(Bf, ci + 1);
        }
    }
#undef LOADCI
#undef FMACI

    const int ob = b * COUT * chs + d * HW + h * W + wbase;
#pragma unroll
    for (int co = 0; co < COUT; ++co) {
#pragma unroll
        for (int wt = 0; wt < WT; ++wt) {
            float v = acc[co][wt];
            if (RELU) v = fmaxf(v, 0.f);
            y[ob + co * chs + wt] = v;
        }
    }
}

// ---------------- softargmin disparity regression ----------------
__global__ __launch_bounds__(256) void dispreg_k(const float* __restrict__ cost,
                                                 float* __restrict__ dsm,
                                                 int total, int D, int HW,
                                                 float dstart, float scale) {
    int idx = blockIdx.x * 256 + threadIdx.x;
    if (idx >= total) return;
    int hw = idx % HW; int b = idx / HW;
    const float* c = cost + b * D * HW + hw;
    float m = -1e30f;
    for (int d = 0; d < D; ++d) m = fmaxf(m, -c[d * HW]);
    float s = 0.f, ws = 0.f;
    for (int d = 0; d < D; ++d) {
        float e = expf(-c[d * HW] - m);
        s += e;
        ws = fmaf(e, dstart + (float)d, ws);
    }
    dsm[idx] = ws / s * scale;
}

// ---------------- bilinear upsample + optional residual + optional depth ----------------
__global__ __launch_bounds__(256) void upsample_add_k(const float* __restrict__ s,
                                                      int sh, int sw,
                                                      const float* __restrict__ prev,
                                                      float* __restrict__ out,
                                                      float* __restrict__ dep) {
    int idx = blockIdx.x * 256 + threadIdx.x;
    if (idx >= NPIX) return;
    int x = idx % FULL_W; int t = idx / FULL_W;
    int y = t % FULL_H; int b = t / FULL_H;
    float fy = (y + 0.5f) * ((float)sh / FULL_H) - 0.5f;
    float fx = (x + 0.5f) * ((float)sw / FULL_W) - 0.5f;
    int y0 = (int)floorf(fy); float wy = fy - (float)y0;
    int x0 = (int)floorf(fx); float wx = fx - (float)x0;
    int y0c = min(max(y0, 0), sh - 1), y1c = min(max(y0 + 1, 0), sh - 1);
    int x0c = min(max(x0, 0), sw - 1), x1c = min(max(x0 + 1, 0), sw - 1);
    const float* sb = s + b * sh * sw;
    float v00 = sb[y0c * sw + x0c], v01 = sb[y0c * sw + x1c];
    float v10 = sb[y1c * sw + x0c], v11 = sb[y1c * sw + x1c];
    float v = (1.f - wy) * ((1.f - wx) * v00 + wx * v01) +
              wy        * ((1.f - wx) * v10 + wx * v11);
    if (prev) v += prev[idx];
    out[idx] = v;
    if (dep) {
        float p = fabsf(v);
        float d = 64.f / p;                 // BASELINE*FOCAL
        if (isnan(d)) d = 100.f;
        d = fminf(fmaxf(d, 0.1f), 100.f);
        dep[idx] = d;
    }
}

// ---------------- antialiased triangle downsample + scale ----------------
__global__ __launch_bounds__(256) void wflow_k(const float* __restrict__ pred,
                                               float* __restrict__ wf,
                                               int oh, int ow, int f, float scale) {
    int idx = blockIdx.x * 256 + threadIdx.x;
    int total = NB * oh * ow;
    if (idx >= total) return;
    int ox = idx % ow; int t = idx / ow;
    int oy = t % oh; int b = t / oh;
    float ff = (float)f, invf = 1.f / (float)f;
    float cy = (oy + 0.5f) * ff - 0.5f;
    float cx = (ox + 0.5f) * ff - 0.5f;
    int ylo = max((int)ceilf(cy - ff), 0);
    int yhi = min((int)floorf(cy + ff), FULL_H - 1);
    int xlo = max((int)ceilf(cx - ff), 0);
    int xhi = min((int)floorf(cx + ff), FULL_W - 1);
    const float* pb = pred + b * FULL_H * FULL_W;
    float acc = 0.f, wys = 0.f, wxs = 0.f;
    for (int iy = ylo; iy <= yhi; ++iy) {
        float wy = 1.f - fabsf((float)iy - cy) * invf;
        wys += wy;
        float rowacc = 0.f;
        const float* row = pb + iy * FULL_W;
        for (int ix = xlo; ix <= xhi; ++ix) {
            float wx = 1.f - fabsf((float)ix - cx) * invf;
            rowacc = fmaf(wx, row[ix], rowacc);
        }
        acc = fmaf(wy, rowacc, acc);
    }
    for (int ix = xlo; ix <= xhi; ++ix) wxs += 1.f - fabsf((float)ix - cx) * invf;
    wf[idx] = acc / (wys * wxs) * scale;
}

static inline dim3 g(int n) { return dim3((n + 255) / 256); }

extern "C" void kernel_launch(void* const* d_in, const int* in_sizes, int n_in,
                              void* d_out, int out_size, void* d_ws, size_t ws_size,
                              hipStream_t stream) {
    const float* f_l0  = (const float*)d_in[0];
    const float* f_r0  = (const float*)d_in[1];
    const float* f_l1  = (const float*)d_in[2];
    const float* f_r1  = (const float*)d_in[3];
    const float* f_l2  = (const float*)d_in[4];
    const float* f_r2  = (const float*)d_in[5];
    const float* w_in0  = (const float*)d_in[6];
    const float* w_mid0 = (const float*)d_in[7];
    const float* w_out0 = (const float*)d_in[8];
    const float* w_in1  = (const float*)d_in[9];
    const float* w_mid1 = (const float*)d_in[10];
    const float* w_out1 = (const float*)d_in[11];
    const float* w_in2  = (const float*)d_in[12];
    const float* w_mid2 = (const float*)d_in[13];
    const float* w_out2 = (const float*)d_in[14];

    float* out   = (float*)d_out;
    float* pred0 = out;
    float* pred1 = out + NPIX;
    float* pred2 = out + 2 * NPIX;
    float* depth = out + 3 * NPIX;

    float* ws = (float*)d_ws;
    float* xA   = ws;                 // 6,553,600 floats (max act: 8*4*5*128*320)
    float* xB   = xA + 6553600;
    float* cost = xB + 6553600;       // 1,638,400
    float* dsm  = cost + 1638400;     // 327,680
    float* wfl  = dsm + 327680;       // 327,680

    dim3 blk(256);

    // ---------------- stage 0 ----------------
    {
        const int D = 12, H = 32, W = 80;
        const int total = NB * D * H * W;          // 245,760
        cost0_k<<<g(total), blk, 0, stream>>>(f_l0, f_r0, cost);
        int ns2 = total / 2;                       // 122,880 -> 480 blocks
        int ns4 = total / 4;                       //  61,440 -> 240 blocks
        convf_k<1, 16, 2, true><<<g(ns2), blk, 0, stream>>>(cost, w_in0, xA, D, H, W, ns2);
        const float* src = xA; float* dst = xB;
        for (int k = 0; k < 4; ++k) {
            convf_k<16, 16, 2, true><<<g(ns2), blk, 0, stream>>>(src, w_mid0 + k * 6912, dst, D, H, W, ns2);
            const float* nsrc = dst; dst = (float*)src; src = nsrc;
        }
        convf_k<16, 1, 4, false><<<g(ns4), blk, 0, stream>>>(src, w_out0, cost, D, H, W, ns4);
        dispreg_k<<<g(NB * H * W), blk, 0, stream>>>(cost, dsm, NB * H * W, D, H * W, 0.f, 16.f);
        upsample_add_k<<<g(NPIX), blk, 0, stream>>>(dsm, H, W, nullptr, pred0, depth);
    }

    // ---------------- stage 1 ----------------
    {
        const int D = 5, H = 64, W = 160;
        const int total = NB * D * H * W;          // 409,600
        wflow_k<<<g(NB * H * W), blk, 0, stream>>>(pred0, wfl, H, W, 8, 0.125f);
        costres_k<<<g(total), blk, 0, stream>>>(f_l1, f_r1, wfl, cost, H, W);
        int ns2 = total / 2;                       // 204,800 -> 800 blocks
        int ns4 = total / 4;                       // 102,400 -> 400 blocks
        convf_k<1, 4, 2, true><<<g(ns2), blk, 0, stream>>>(cost, w_in1, xA, D, H, W, ns2);
        const float* src = xA; float* dst = xB;
        for (int k = 0; k < 4; ++k) {
            convf_k<4, 4, 2, true><<<g(ns2), blk, 0, stream>>>(src, w_mid1 + k * 432, dst, D, H, W, ns2);
            const float* nsrc = dst; dst = (float*)src; src = nsrc;
        }
        convf_k<4, 1, 4, false><<<g(ns4), blk, 0, stream>>>(src, w_out1, cost, D, H, W, ns4);
        dispreg_k<<<g(NB * H * W), blk, 0, stream>>>(cost, dsm, NB * H * W, D, H * W, -2.f, 8.f);
        upsample_add_k<<<g(NPIX), blk, 0, stream>>>(dsm, H, W, pred0, pred1, nullptr);
    }

    // ---------------- stage 2 ----------------
    {
        const int D = 5, H = 128, W = 320;
        const int total = NB * D * H * W;          // 1,638,400
        wflow_k<<<g(NB * H * W), blk, 0, stream>>>(pred1, wfl, H, W, 4, 0.25f);
        costres_k<<<g(total), blk, 0, stream>>>(f_l2, f_r2, wfl, cost, H, W);
        int ns4 = total / 4;                       // 409,600 -> 1600 blocks
        convf_k<1, 4, 4, true><<<g(ns4), blk, 0, stream>>>(cost, w_in2, xA, D, H, W, ns4);
        const float* src = xA; float* dst = xB;
        for (int k = 0; k < 4; ++k) {
            convf_k<4, 4, 4, true><<<g(ns4), blk, 0, stream>>>(src, w_mid2 + k * 432, dst, D, H, W, ns4);
            const float* nsrc = dst; dst = (float*)src; src = nsrc;
        }
        convf_k<4, 1, 4, false><<<g(ns4), blk, 0, stream>>>(src, w_out2, cost, D, H, W, ns4);
        dispreg_k<<<g(NB * H * W), blk, 0, stream>>>(cost, dsm, NB * H * W, D, H * W, -2.f, 4.f);
        upsample_add_k<<<g(NPIX), blk, 0, stream>>>(dsm, H, W, pred1, pred2, nullptr);
    }
}

// Round 10
// 1385.052 us; speedup vs baseline: 4.5239x; 4.5239x over previous
//
#include <hip/hip_runtime.h>
#include <math.h>

// AnyNet stereo forward, fp32. Round 10: LDS-tiled conv3d (canonical pattern).
// Block stages a (TD+2)x(TH+2)x(TW+2) input tile per channel-group into LDS
// (masked at staging), weights in LDS broadcast; threads compute w-pairs from
// LDS with ~10x reuse. No launch_bounds min-wave caps (R9 lesson), no padded
// buffers, no memsets.

#define FULL_H 512
#define FULL_W 1280
#define NB 8
#define NPIX (NB * FULL_H * FULL_W)   // 5,242,880

// ---------------- stage-0 L1 cost volume ----------------
__global__ __launch_bounds__(256) void cost0_k(const float* __restrict__ fl,
                                               const float* __restrict__ fr,
                                               float* __restrict__ cost) {
    const int H = 32, W = 80, D = 12, C = 8;
    int idx = blockIdx.x * 256 + threadIdx.x;
    int total = NB * D * H * W;
    if (idx >= total) return;
    int w = idx % W; int t = idx / W;
    int h = t % H; t /= H;
    int d = t % D; int b = t / D;
    int src = w - d;
    float acc = 0.f;
    for (int c = 0; c < C; ++c) {
        int base = ((b * C + c) * H + h) * W;
        float flv = fl[base + w];
        float frv = (src >= 0) ? fr[base + src] : 0.f;
        acc += fabsf(flv - frv);
    }
    cost[((b * D + d) * H + h) * W + w] = acc;
}

// ---------------- residual (warped) cost volume ----------------
__global__ __launch_bounds__(256) void costres_k(const float* __restrict__ fl,
                                                 const float* __restrict__ fr,
                                                 const float* __restrict__ wf,
                                                 float* __restrict__ cost,
                                                 int H, int W) {
    const int C = 8, S = 5;
    int idx = blockIdx.x * 256 + threadIdx.x;
    int total = NB * S * H * W;
    if (idx >= total) return;
    int w = idx % W; int t = idx / W;
    int h = t % H; t /= H;
    int s = t % S; int b = t / S;
    float disp  = wf[(b * H + h) * W + w];
    float shift = (float)(s - 2);
    float xs  = (float)w - (disp - shift);
    float x0f = floorf(xs);
    float w1  = xs - x0f;
    float x0fc = fminf(fmaxf(x0f, -2.f), (float)W);
    int x0 = (int)x0fc;
    int x1 = x0 + 1;
    float m0 = (x0 >= 0 && x0 <= W - 1) ? (1.f - w1) : 0.f;
    float m1 = (x1 >= 0 && x1 <= W - 1) ? w1 : 0.f;
    int x0c = min(max(x0, 0), W - 1);
    int x1c = min(max(x1, 0), W - 1);
    float acc = 0.f;
    const float* flb = fl + ((b * C) * H + h) * W;
    const float* frb = fr + ((b * C) * H + h) * W;
    for (int c = 0; c < C; ++c) {
        float v = frb[x0c] * m0 + frb[x1c] * m1;
        acc += fabsf(flb[w] - v);
        flb += H * W;
        frb += H * W;
    }
    cost[idx] = acc;
}

// ---------------- LDS-tiled 3x3x3 SAME conv3d ----------------
// x: [B,CIN,D,H,W]  wg: [COUT,CIN,27]  y: [B,COUT,D,H,W]
// Block tile TDxTHxTW voxels; input staged per CIG channel group with halo
// and zero-masking; weights in LDS [ci][tap][co]. Each thread owns VPT2
// w-pair slots x all COUT. Requires D%TD==0 (or TD==D), H%TH==0, W%TW==0,
// TD*TH*TW == 512*VPT2.
template <int CIN, int COUT, int CIG, int TD, int TH, int TW, int VPT2, bool RELU>
__global__ __launch_bounds__(256) void convt_k(const float* __restrict__ x,
                                               const float* __restrict__ wg,
                                               float* __restrict__ y,
                                               int D, int H, int W) {
    constexpr int HZ = TH + 2, WZ = TW + 2, DZ = TD + 2;
    constexpr int TILE = DZ * HZ * WZ;
    constexpr int WPH = TW / 2;            // w-pairs per row
    __shared__ __align__(16) float xs[CIG * TILE];
    __shared__ __align__(16) float wl[CIN * 27 * COUT];

    for (int i = threadIdx.x; i < CIN * 27 * COUT; i += 256) {
        int co = i % COUT; int rest = i / COUT;
        int tap = rest % 27; int ci = rest / 27;
        wl[i] = wg[(co * CIN + ci) * 27 + tap];
    }

    const int nw = W / TW, nh = H / TH, nd = D / TD;
    int bid = blockIdx.x;
    const int wt = bid % nw; bid /= nw;
    const int ht = bid % nh; bid /= nh;
    const int dt = bid % nd; const int b = bid / nd;
    const int HW = H * W;

    // per-slot voxel coords (local tile coords)
    int sdz[VPT2], shz[VPT2], swp[VPT2];
#pragma unroll
    for (int s = 0; s < VPT2; ++s) {
        int vp = threadIdx.x + s * 256;
        swp[s] = vp % WPH; int rest = vp / WPH;
        shz[s] = rest % TH; sdz[s] = rest / TH;
    }

    float acc[COUT][VPT2][2];
#pragma unroll
    for (int co = 0; co < COUT; ++co)
#pragma unroll
        for (int s = 0; s < VPT2; ++s) { acc[co][s][0] = 0.f; acc[co][s][1] = 0.f; }

    __syncthreads();   // weights ready

    for (int cig0 = 0; cig0 < CIN; cig0 += CIG) {
        if (cig0) __syncthreads();         // previous compute done
        // ---- stage CIG channels (masked, coalesced-ish) ----
        for (int i = threadIdx.x; i < CIG * TILE; i += 256) {
            int ci_ = i / TILE; int r = i - ci_ * TILE;
            int dz = r / (HZ * WZ); int r2 = r - dz * (HZ * WZ);
            int hz = r2 / WZ; int wz = r2 - hz * WZ;
            int gd = dt * TD + dz - 1;
            int gh = ht * TH + hz - 1;
            int gw = wt * TW + wz - 1;
            float m = (((unsigned)gd < (unsigned)D) &&
                       ((unsigned)gh < (unsigned)H) &&
                       ((unsigned)gw < (unsigned)W)) ? 1.f : 0.f;
            int gdc = min(max(gd, 0), D - 1);
            int ghc = min(max(gh, 0), H - 1);
            int gwc = min(max(gw, 0), W - 1);
            xs[i] = x[((size_t)(b * CIN + cig0 + ci_) * D + gdc) * HW + ghc * W + gwc] * m;
        }
        __syncthreads();
        // ---- compute from LDS ----
        for (int cil = 0; cil < CIG; ++cil) {
            const float* xb_ = xs + cil * TILE;
            const float* wb_ = wl + (size_t)(cig0 + cil) * 27 * COUT;
#pragma unroll
            for (int r = 0; r < 9; ++r) {
                const int kd = r / 3, kh = r % 3;
                float xr[VPT2][4];
#pragma unroll
                for (int s = 0; s < VPT2; ++s) {
                    const float* rowp = xb_ + (sdz[s] + kd) * (HZ * WZ)
                                      + (shz[s] + kh) * WZ + swp[s] * 2;
                    float2 pa = *reinterpret_cast<const float2*>(rowp);
                    float2 pb = *reinterpret_cast<const float2*>(rowp + 2);
                    xr[s][0] = pa.x; xr[s][1] = pa.y;
                    xr[s][2] = pb.x; xr[s][3] = pb.y;
                }
#pragma unroll
                for (int kw = 0; kw < 3; ++kw) {
                    const float* wq = wb_ + (r * 3 + kw) * COUT;
                    if constexpr (COUT == 1) {
                        float wv = wq[0];
#pragma unroll
                        for (int s = 0; s < VPT2; ++s) {
                            acc[0][s][0] = fmaf(xr[s][kw],     wv, acc[0][s][0]);
                            acc[0][s][1] = fmaf(xr[s][kw + 1], wv, acc[0][s][1]);
                        }
                    } else {
#pragma unroll
                        for (int q = 0; q < COUT / 4; ++q) {
                            float4 w4 = reinterpret_cast<const float4*>(wq)[q];
#pragma unroll
                            for (int s = 0; s < VPT2; ++s) {
                                float xv0 = xr[s][kw], xv1 = xr[s][kw + 1];
                                acc[q*4+0][s][0] = fmaf(xv0, w4.x, acc[q*4+0][s][0]);
                                acc[q*4+0][s][1] = fmaf(xv1, w4.x, acc[q*4+0][s][1]);
                                acc[q*4+1][s][0] = fmaf(xv0, w4.y, acc[q*4+1][s][0]);
                                acc[q*4+1][s][1] = fmaf(xv1, w4.y, acc[q*4+1][s][1]);
                                acc[q*4+2][s][0] = fmaf(xv0, w4.z, acc[q*4+2][s][0]);
                                acc[q*4+2][s][1] = fmaf(xv1, w4.z, acc[q*4+2][s][1]);
                                acc[q*4+3][s][0] = fmaf(xv0, w4.w, acc[q*4+3][s][0]);
                                acc[q*4+3][s][1] = fmaf(xv1, w4.w, acc[q*4+3][s][1]);
                            }
                        }
                    }
                }
            }
        }
    }

    // ---- write outputs (float2 per co per slot) ----
#pragma unroll
    for (int s = 0; s < VPT2; ++s) {
        const int od = dt * TD + sdz[s];
        const int oh = ht * TH + shz[s];
        const int ow = wt * TW + swp[s] * 2;
#pragma unroll
        for (int co = 0; co < COUT; ++co) {
            float2 v;
            v.x = acc[co][s][0]; v.y = acc[co][s][1];
            if (RELU) { v.x = fmaxf(v.x, 0.f); v.y = fmaxf(v.y, 0.f); }
            *reinterpret_cast<float2*>(
                &y[((size_t)(b * COUT + co) * D + od) * HW + oh * W + ow]) = v;
        }
    }
}

// ---------------- softargmin disparity regression ----------------
__global__ __launch_bounds__(256) void dispreg_k(const float* __restrict__ cost,
                                                 float* __restrict__ dsm,
                                                 int total, int D, int HW,
                                                 float dstart, float scale) {
    int idx = blockIdx.x * 256 + threadIdx.x;
    if (idx >= total) return;
    int hw = idx % HW; int b = idx / HW;
    const float* c = cost + b * D * HW + hw;
    float m = -1e30f;
    for (int d = 0; d < D; ++d) m = fmaxf(m, -c[d * HW]);
    float s = 0.f, ws = 0.f;
    for (int d = 0; d < D; ++d) {
        float e = expf(-c[d * HW] - m);
        s += e;
        ws = fmaf(e, dstart + (float)d, ws);
    }
    dsm[idx] = ws / s * scale;
}

// ---------------- bilinear upsample + optional residual + optional depth ----------------
__global__ __launch_bounds__(256) void upsample_add_k(const float* __restrict__ s,
                                                      int sh, int sw,
                                                      const float* __restrict__ prev,
                                                      float* __restrict__ out,
                                                      float* __restrict__ dep) {
    int idx = blockIdx.x * 256 + threadIdx.x;
    if (idx >= NPIX) return;
    int x = idx % FULL_W; int t = idx / FULL_W;
    int y = t % FULL_H; int b = t / FULL_H;
    float fy = (y + 0.5f) * ((float)sh / FULL_H) - 0.5f;
    float fx = (x + 0.5f) * ((float)sw / FULL_W) - 0.5f;
    int y0 = (int)floorf(fy); float wy = fy - (float)y0;
    int x0 = (int)floorf(fx); float wx = fx - (float)x0;
    int y0c = min(max(y0, 0), sh - 1), y1c = min(max(y0 + 1, 0), sh - 1);
    int x0c = min(max(x0, 0), sw - 1), x1c = min(max(x0 + 1, 0), sw - 1);
    const float* sb = s + b * sh * sw;
    float v00 = sb[y0c * sw + x0c], v01 = sb[y0c * sw + x1c];
    float v10 = sb[y1c * sw + x0c], v11 = sb[y1c * sw + x1c];
    float v = (1.f - wy) * ((1.f - wx) * v00 + wx * v01) +
              wy        * ((1.f - wx) * v10 + wx * v11);
    if (prev) v += prev[idx];
    out[idx] = v;
    if (dep) {
        float p = fabsf(v);
        float d = 64.f / p;                 // BASELINE*FOCAL
        if (isnan(d)) d = 100.f;
        d = fminf(fmaxf(d, 0.1f), 100.f);
        dep[idx] = d;
    }
}

// ---------------- antialiased triangle downsample + scale ----------------
__global__ __launch_bounds__(256) void wflow_k(const float* __restrict__ pred,
                                               float* __restrict__ wf,
                                               int oh, int ow, int f, float scale) {
    int idx = blockIdx.x * 256 + threadIdx.x;
    int total = NB * oh * ow;
    if (idx >= total) return;
    int ox = idx % ow; int t = idx / ow;
    int oy = t % oh; int b = t / oh;
    float ff = (float)f, invf = 1.f / (float)f;
    float cy = (oy + 0.5f) * ff - 0.5f;
    float cx = (ox + 0.5f) * ff - 0.5f;
    int ylo = max((int)ceilf(cy - ff), 0);
    int yhi = min((int)floorf(cy + ff), FULL_H - 1);
    int xlo = max((int)ceilf(cx - ff), 0);
    int xhi = min((int)floorf(cx + ff), FULL_W - 1);
    const float* pb = pred + b * FULL_H * FULL_W;
    float acc = 0.f, wys = 0.f, wxs = 0.f;
    for (int iy = ylo; iy <= yhi; ++iy) {
        float wy = 1.f - fabsf((float)iy - cy) * invf;
        wys += wy;
        float rowacc = 0.f;
        const float* row = pb + iy * FULL_W;
        for (int ix = xlo; ix <= xhi; ++ix) {
            float wx = 1.f - fabsf((float)ix - cx) * invf;
            rowacc = fmaf(wx, row[ix], rowacc);
        }
        acc = fmaf(wy, rowacc, acc);
    }
    for (int ix = xlo; ix <= xhi; ++ix) wxs += 1.f - fabsf((float)ix - cx) * invf;
    wf[idx] = acc / (wys * wxs) * scale;
}

static inline dim3 g(int n) { return dim3((n + 255) / 256); }

extern "C" void kernel_launch(void* const* d_in, const int* in_sizes, int n_in,
                              void* d_out, int out_size, void* d_ws, size_t ws_size,
                              hipStream_t stream) {
    const float* f_l0  = (const float*)d_in[0];
    const float* f_r0  = (const float*)d_in[1];
    const float* f_l1  = (const float*)d_in[2];
    const float* f_r1  = (const float*)d_in[3];
    const float* f_l2  = (const float*)d_in[4];
    const float* f_r2  = (const float*)d_in[5];
    const float* w_in0  = (const float*)d_in[6];
    const float* w_mid0 = (const float*)d_in[7];
    const float* w_out0 = (const float*)d_in[8];
    const float* w_in1  = (const float*)d_in[9];
    const float* w_mid1 = (const float*)d_in[10];
    const float* w_out1 = (const float*)d_in[11];
    const float* w_in2  = (const float*)d_in[12];
    const float* w_mid2 = (const float*)d_in[13];
    const float* w_out2 = (const float*)d_in[14];

    float* out   = (float*)d_out;
    float* pred0 = out;
    float* pred1 = out + NPIX;
    float* pred2 = out + 2 * NPIX;
    float* depth = out + 3 * NPIX;

    float* ws = (float*)d_ws;
    float* xA   = ws;                 // 6,553,600 floats
    float* xB   = xA + 6553600;
    float* cost = xB + 6553600;       // 1,638,400
    float* dsm  = cost + 1638400;     // 327,680
    float* wfl  = dsm + 327680;       // 327,680

    dim3 blk(256);

    // ---------------- stage 0 (D=12,H=32,W=80; tile 4x8x16, 480 blocks) ----------------
    {
        const int D = 12, H = 32, W = 80;
        const int total = NB * D * H * W;
        const int blocks = NB * (D / 4) * (H / 8) * (W / 16);   // 480
        cost0_k<<<g(total), blk, 0, stream>>>(f_l0, f_r0, cost);
        convt_k<1, 16, 1, 4, 8, 16, 1, true><<<blocks, blk, 0, stream>>>(cost, w_in0, xA, D, H, W);
        const float* src = xA; float* dst = xB;
        for (int k = 0; k < 4; ++k) {
            convt_k<16, 16, 8, 4, 8, 16, 1, true><<<blocks, blk, 0, stream>>>(src, w_mid0 + k * 6912, dst, D, H, W);
            const float* nsrc = dst; dst = (float*)src; src = nsrc;
        }
        convt_k<16, 1, 8, 4, 8, 16, 1, false><<<blocks, blk, 0, stream>>>(src, w_out0, cost, D, H, W);
        dispreg_k<<<g(NB * H * W), blk, 0, stream>>>(cost, dsm, NB * H * W, D, H * W, 0.f, 16.f);
        upsample_add_k<<<g(NPIX), blk, 0, stream>>>(dsm, H, W, nullptr, pred0, depth);
    }

    // ---------------- stage 1 (D=5,H=64,W=160; tile 5x16x32, 160 blocks) ----------------
    {
        const int D = 5, H = 64, W = 160;
        const int total = NB * D * H * W;
        const int blocks = NB * 1 * (H / 16) * (W / 32);        // 160
        wflow_k<<<g(NB * H * W), blk, 0, stream>>>(pred0, wfl, H, W, 8, 0.125f);
        costres_k<<<g(total), blk, 0, stream>>>(f_l1, f_r1, wfl, cost, H, W);
        convt_k<1, 4, 1, 5, 16, 32, 5, true><<<blocks, blk, 0, stream>>>(cost, w_in1, xA, D, H, W);
        const float* src = xA; float* dst = xB;
        for (int k = 0; k < 4; ++k) {
            convt_k<4, 4, 2, 5, 16, 32, 5, true><<<blocks, blk, 0, stream>>>(src, w_mid1 + k * 432, dst, D, H, W);
            const float* nsrc = dst; dst = (float*)src; src = nsrc;
        }
        convt_k<4, 1, 2, 5, 16, 32, 5, false><<<blocks, blk, 0, stream>>>(src, w_out1, cost, D, H, W);
        dispreg_k<<<g(NB * H * W), blk, 0, stream>>>(cost, dsm, NB * H * W, D, H * W, -2.f, 8.f);
        upsample_add_k<<<g(NPIX), blk, 0, stream>>>(dsm, H, W, pred0, pred1, nullptr);
    }

    // ---------------- stage 2 (D=5,H=128,W=320; tile 5x16x32, 640 blocks) ----------------
    {
        const int D = 5, H = 128, W = 320;
        const int total = NB * D * H * W;
        const int blocks = NB * 1 * (H / 16) * (W / 32);        // 640
        wflow_k<<<g(NB * H * W), blk, 0, stream>>>(pred1, wfl, H, W, 4, 0.25f);
        costres_k<<<g(total), blk, 0, stream>>>(f_l2, f_r2, wfl, cost, H, W);
        convt_k<1, 4, 1, 5, 16, 32, 5, true><<<blocks, blk, 0, stream>>>(cost, w_in2, xA, D, H, W);
        const float* src = xA; float* dst = xB;
        for (int k = 0; k < 4; ++k) {
            convt_k<4, 4, 2, 5, 16, 32, 5, true><<<blocks, blk, 0, stream>>>(src, w_mid2 + k * 432, dst, D, H, W);
            const float* nsrc = dst; dst = (float*)src; src = nsrc;
        }
        convt_k<4, 1, 2, 5, 16, 32, 5, false><<<blocks, blk, 0, stream>>>(src, w_out2, cost, D, H, W);
        dispreg_k<<<g(NB * H * W), blk, 0, stream>>>(cost, dsm, NB * H * W, D, H * W, -2.f, 4.f);
        upsample_add_k<<<g(NPIX), blk, 0, stream>>>(dsm, H, W, pred1, pred2, nullptr);
    }
}